// Round 7
// baseline (154.570 us; speedup 1.0000x reference)
//
#include <hip/hip_runtime.h>
#include <math.h>

#define EPS      0.1f
#define INV_EPS  10.0f
#define THRESH   0.1f
#define MAX_IT   20

// Problem sizes (fixed by reference setup_inputs)
#define BB 4
#define NN 1024
#define MM 1024
#define DD 512

#define MU_P (1.0f / 1024.0f + 1e-8f)

// Fused gemm+sinkhorn: 128 blocks x 512 threads, 32 rows/block, 4 rows/wave
#define GBLK 128
#define TBLK 512

// workspace layout (float offsets) — no global K buffer
#define OFF_XB   ((size_t)0)               // x in bf16 [B,N,D] (4.2 MB)
#define OFF_YB   ((size_t)1048576)         // y in bf16 [B,M,D] (4.2 MB)
#define OFF_NX   ((size_t)2097152)         // |x_i| [B*N]
#define OFF_NY   (OFF_NX + 4096)           // |y_j| [B*M]
#define OFF_NUP  (OFF_NY + 4096)           // nu + 1e-8 [B*M]
#define OFF_CS   (OFF_NUP + 4096)          // colsum rotation [3][4096]
#define OFF_CNT  (OFF_CS + 12288)          // arrival counters [3][16] u64 (384 B)

#define ALDA 520   // padded A-stage stride (halves): bank-optimal b128 frag reads
#define KLDA 1032  // padded K-strip stride (halves)

#define ERR_MASK ((1ULL << 44) - 1)

typedef __bf16 bf16x8 __attribute__((ext_vector_type(8)));
typedef float f32x4 __attribute__((ext_vector_type(4)));
typedef unsigned long long u64;

__device__ __forceinline__ float wave_reduce_sum(float x) {
#pragma unroll
  for (int off = 32; off > 0; off >>= 1) x += __shfl_xor(x, off, 64);
  return x;
}

// pack two floats to bf16x2 (RNE via compiler cast)
__device__ __forceinline__ uint pk2(float a, float b) {
  __bf16 ha = (__bf16)a, hb = (__bf16)b;
  return (uint)*(ushort*)&ha | ((uint)*(ushort*)&hb << 16);
}

__device__ __forceinline__ void unpack8(uint4 k, float* kf) {
  kf[0] = __uint_as_float(k.x << 16);
  kf[1] = __uint_as_float(k.x & 0xffff0000u);
  kf[2] = __uint_as_float(k.y << 16);
  kf[3] = __uint_as_float(k.y & 0xffff0000u);
  kf[4] = __uint_as_float(k.z << 16);
  kf[5] = __uint_as_float(k.z & 0xffff0000u);
  kf[6] = __uint_as_float(k.w << 16);
  kf[7] = __uint_as_float(k.w & 0xffff0000u);
}

// -------- prep: fp32 norms of x/y rows, x/y -> bf16, sinkhorn state init.
// Kernel boundary after this = device-scope release (proven rounds 0-6). --------
__global__ void __launch_bounds__(256) prep_kernel(const float* __restrict__ x,
                                                   const float* __restrict__ y,
                                                   ushort* __restrict__ xb,
                                                   ushort* __restrict__ yb,
                                                   float* __restrict__ nx,
                                                   float* __restrict__ ny,
                                                   const float* __restrict__ nu,
                                                   float* nup, float* colsum,
                                                   int* cnti, float* out) {
  const int tid = threadIdx.x;
  int gt = blockIdx.x * 256 + tid;
  if (gt < BB * MM) {
    nup[gt] = nu[gt] + 1e-8f;
    colsum[4096 + gt] = 0.f;      // buf1 is iteration 0's add target
  }
  if (gt < 96) cnti[gt] = 0;      // 3 x 16 u64 counter slots
  if (gt < BB) out[gt] = 0.f;

  const int w = tid >> 6, lane = tid & 63;
  const int r = blockIdx.x * 4 + w;                 // 0..8191
  const bool isx = (r < BB * NN);
  const float* src = isx ? (x + (size_t)r * DD)
                         : (y + (size_t)(r - BB * NN) * DD);
  ushort* dst = isx ? (xb + (size_t)r * DD)
                    : (yb + (size_t)(r - BB * NN) * DD);
  const float4* s4 = (const float4*)src;
  float4 a = s4[lane * 2];          // 8 contiguous floats per lane
  float4 b = s4[lane * 2 + 1];
  float ss = a.x * a.x + a.y * a.y + a.z * a.z + a.w * a.w +
             b.x * b.x + b.y * b.y + b.z * b.z + b.w * b.w;
  uint4 pk = make_uint4(pk2(a.x, a.y), pk2(a.z, a.w), pk2(b.x, b.y), pk2(b.z, b.w));
  *(uint4*)(dst + lane * 8) = pk;
  ss = wave_reduce_sum(ss);
  if (lane == 0) {
    float n = sqrtf(ss);
    if (isx) nx[r] = n; else ny[r - BB * NN] = n;
  }
}

// -------- fused strip-GEMM + persistent Sinkhorn (cooperative) --------
// phase 1: block computes its 32 K-rows (32x1024) into LDS via MFMA (R5/R6 proven).
// phase 2: sinkhorn with COUNTER barrier: per iteration, each block's tid0 adds
//   (1<<44)|err_fixed to cnt[it%3][batch]; pollers read 4 u64 (one coalesced
//   32B request/wave) until all counts==32. Drain order preserved from the
//   proven flag scheme: colsum atomics -> zero rotation slots -> vmcnt(0) ->
//   __syncthreads -> tid0 signal. Count==32 therefore implies colsum complete.
//   wv lives in REGISTERS (per-lane colsum/nup slices) -> no s_v staging and
//   no post-poll barrier; 2 barriers/iter instead of 3.
__global__ void __launch_bounds__(TBLK, 2) fused_kernel(
    const ushort* __restrict__ xb, const ushort* __restrict__ yb,
    const float* __restrict__ nx, const float* __restrict__ ny,
    float* __restrict__ colsum, const float* __restrict__ nup,
    u64* __restrict__ cnt, float* __restrict__ out) {
  const int tid = threadIdx.x;
  const int bid = blockIdx.x;
  const int lane = tid & 63;
  const int w = tid >> 6;                 // 0..7
  const int m16 = lane & 15, q = lane >> 4;
  const int batch = bid >> 5;             // identity mapping
  const int rbase = (bid & 31) * 32;      // 32 owned rows

  __shared__ alignas(16) ushort As[32 * ALDA];      // 33.3 KB padded A stage
  __shared__ alignas(16) ushort kstrip[32 * KLDA];  // 66 KB K strip; spart alias
  __shared__ alignas(16) float s_ny[1024];          // ny norms (gemm epilogue)
  __shared__ float s_nx[32];
  __shared__ float swerr[2][8];                     // per-wave err, ping-pong
  float* spart = (float*)kstrip;                    // [8][1024] in sinkhorn phase

  // ---------------- phase 1: strip GEMM into LDS ----------------
  {
    if (tid < 32) s_nx[tid] = nx[batch * NN + rbase + tid];
    s_ny[tid] = ny[batch * MM + tid];
    s_ny[tid + 512] = ny[batch * MM + tid + 512];

    // stage A strip (32 rows x 512 halves, contiguous in xb) into padded LDS
    {
      const ushort* xs = xb + ((size_t)batch * NN + rbase) * DD;
      const int row = tid >> 4;          // 16 threads per row
      const int c0 = (tid & 15) * 32;    // 32 halves each
#pragma unroll
      for (int i = 0; i < 4; ++i) {
        uint4 v = *(const uint4*)(xs + (size_t)row * DD + c0 + i * 8);
        *(uint4*)&As[row * ALDA + c0 + i * 8] = v;
      }
    }
    __syncthreads();

    // wave w owns cols [w*128, w*128+128), all 32 rows (2 row-tiles)
    const int j0 = w * 128;
    const ushort* brow = yb + ((size_t)batch * MM + j0 + m16) * DD + q * 8;
    f32x4 acc[2][8];
#pragma unroll
    for (int rt = 0; rt < 2; ++rt)
#pragma unroll
      for (int ni = 0; ni < 8; ++ni) acc[rt][ni] = (f32x4)0.f;

#pragma unroll
    for (int ks = 0; ks < 16; ++ks) {
      bf16x8 a0 = *(const bf16x8*)&As[(m16)*ALDA + ks * 32 + q * 8];
      bf16x8 a1 = *(const bf16x8*)&As[(16 + m16) * ALDA + ks * 32 + q * 8];
      bf16x8 bfr[8];
#pragma unroll
      for (int ni = 0; ni < 8; ++ni)
        bfr[ni] = *(const bf16x8*)(brow + (size_t)ni * 16 * DD + ks * 32);
#pragma unroll
      for (int ni = 0; ni < 8; ++ni)
        acc[0][ni] = __builtin_amdgcn_mfma_f32_16x16x32_bf16(a0, bfr[ni], acc[0][ni], 0, 0, 0);
#pragma unroll
      for (int ni = 0; ni < 8; ++ni)
        acc[1][ni] = __builtin_amdgcn_mfma_f32_16x16x32_bf16(a1, bfr[ni], acc[1][ni], 0, 0, 0);
    }

    // epilogue: K = exp(-(1 - dot/den)/eps) -> LDS bf16
#pragma unroll
    for (int rt = 0; rt < 2; ++rt)
#pragma unroll
      for (int ni = 0; ni < 8; ++ni)
#pragma unroll
        for (int r = 0; r < 4; ++r) {
          const int row = rt * 16 + q * 4 + r;
          const int col = j0 + ni * 16 + m16;
          float den = fmaxf(s_nx[row] * s_ny[col], 1e-8f);
          float cv = 1.0f - acc[rt][ni][r] / den;
          float kv = __expf(-cv * INV_EPS);
          __bf16 hb = (__bf16)kv;
          kstrip[row * KLDA + col] = *(ushort*)&hb;
        }
    __syncthreads();   // strip complete before cross-wave per-wave reg loads
  }

  // ---- each wave loads its 4 rows into registers (64 VGPR), fp32 ----
  float kfr[4][16];
#pragma unroll
  for (int rr = 0; rr < 4; ++rr) {
    const int base = (w * 4 + rr) * KLDA;
    uint4 p;
    p = *(const uint4*)&kstrip[base + 8 * lane];       unpack8(p, kfr[rr]);
    p = *(const uint4*)&kstrip[base + 512 + 8 * lane]; unpack8(p, kfr[rr] + 8);
  }
  // kstrip memory is reused as spart[8][1024] from here on; the first
  // __syncthreads() inside the loop orders spart writes after the kfr reads.

  // ---- preload this lane's nu' slice (cols 8*lane.. and 512+8*lane..) ----
  float nupr[16];
  {
    const float* np = nup + batch * MM;
    *(float4*)&nupr[0]  = *(const float4*)(np + lane * 8);
    *(float4*)&nupr[4]  = *(const float4*)(np + lane * 8 + 4);
    *(float4*)&nupr[8]  = *(const float4*)(np + 512 + lane * 8);
    *(float4*)&nupr[12] = *(const float4*)(np + 512 + lane * 8 + 4);
  }

  // ---------------- phase 2: persistent Sinkhorn ----------------
  const float eps_log_mu = EPS * __logf(MU_P);
  float u_prev[4] = {0.f, 0.f, 0.f, 0.f};
  float wu_reg[4] = {0.f, 0.f, 0.f, 0.f};
  float wvr[16];

  for (int it = 0; it <= MAX_IT; ++it) {
    if (it > 0) {
      // ---- poll arrival counter of iteration it-1 (slot (it-1)%3) ----
      const u64* cs_cnt = cnt + ((it - 1) % 3) * 16;
      u64 v;
      for (;;) {
        v = __hip_atomic_load(cs_cnt + (lane & 3), __ATOMIC_RELAXED, __HIP_MEMORY_SCOPE_AGENT);
        if (__all((v >> 44) >= 32ull)) break;
        __builtin_amdgcn_s_sleep(1);
      }
      // global err of iteration it-1 (4 batch sums, fixed point 1/4096)
      float e = (float)(v & ERR_MASK) * (1.0f / 4096.0f);
      e += __shfl_xor(e, 1, 64);
      e += __shfl_xor(e, 2, 64);
      const bool conv = (e * (1.0f / (float)BB) < THRESH);
      // ---- wv for this iteration, fully in registers ----
      const float* cs = colsum + (it % 3) * 4096 + batch * MM;
      float4 c0 = *(const float4*)(cs + lane * 8);
      float4 c1 = *(const float4*)(cs + lane * 8 + 4);
      float4 c2 = *(const float4*)(cs + 512 + lane * 8);
      float4 c3 = *(const float4*)(cs + 512 + lane * 8 + 4);
      wvr[0] = nupr[0] / c0.x;  wvr[1] = nupr[1] / c0.y;
      wvr[2] = nupr[2] / c0.z;  wvr[3] = nupr[3] / c0.w;
      wvr[4] = nupr[4] / c1.x;  wvr[5] = nupr[5] / c1.y;
      wvr[6] = nupr[6] / c1.z;  wvr[7] = nupr[7] / c1.w;
      wvr[8] = nupr[8] / c2.x;  wvr[9] = nupr[9] / c2.y;
      wvr[10] = nupr[10] / c2.z; wvr[11] = nupr[11] / c2.w;
      wvr[12] = nupr[12] / c3.x; wvr[13] = nupr[13] / c3.y;
      wvr[14] = nupr[14] / c3.z; wvr[15] = nupr[15] / c3.w;
      if (conv || it == MAX_IT) break;   // wvr holds the converged wv
    } else {
#pragma unroll
      for (int t2 = 0; t2 < 16; ++t2) wvr[t2] = 1.f;   // it=0: v=0 -> wv=1
    }

    // ---- rowsum / u-update / colsum partials ----
    float creg[16];
#pragma unroll
    for (int t2 = 0; t2 < 16; ++t2) creg[t2] = 0.f;
    float werr = 0.f;
#pragma unroll
    for (int rr = 0; rr < 4; ++rr) {
      float s = 0.f;
#pragma unroll
      for (int t2 = 0; t2 < 16; ++t2) s = fmaf(kfr[rr][t2], wvr[t2], s);
      s = wave_reduce_sum(s);
      float unv = eps_log_mu - EPS * __logf(s);
      werr += fabsf(unv - u_prev[rr]);
      u_prev[rr] = unv;
      float wu = MU_P / s;              // exp(u_new/eps), exactly
      wu_reg[rr] = wu;
#pragma unroll
      for (int t2 = 0; t2 < 16; ++t2) creg[t2] = fmaf(wu, kfr[rr][t2], creg[t2]);
    }
    if (lane == 0) swerr[it & 1][w] = werr;   // uniform across wave; plain store

    // publish per-wave column partials to LDS (aliased kstrip)
    {
      float* pr = spart + w * 1024;
      *(float4*)&pr[lane * 8] = *(float4*)&creg[0];
      *(float4*)&pr[lane * 8 + 4] = *(float4*)&creg[4];
      *(float4*)&pr[512 + lane * 8] = *(float4*)&creg[8];
      *(float4*)&pr[512 + lane * 8 + 4] = *(float4*)&creg[12];
    }
    __syncthreads();

    // cross-wave reduce + atomic add into next colsum; zero rotation buffers
    {
      float* csn = colsum + ((it + 1) % 3) * 4096 + batch * MM;
      const int j0 = tid * 2;
      float s0 = 0.f, s1 = 0.f;
#pragma unroll
      for (int ww = 0; ww < 8; ++ww) {
        float2 p = *(const float2*)&spart[ww * 1024 + j0];
        s0 += p.x;
        s1 += p.y;
      }
      unsafeAtomicAdd(&csn[j0], s0);
      unsafeAtomicAdd(&csn[j0 + 1], s1);
      if (tid < 32) {
        float* csz = colsum + ((it + 2) % 3) * 4096;
        __hip_atomic_store(&csz[bid * 32 + tid], 0.f, __ATOMIC_RELAXED, __HIP_MEMORY_SCOPE_AGENT);
      }
      // counter slot (it+1)%3 is dead (gen it-2 fully polled): zero before drain
      if (tid < 4)
        __hip_atomic_store(&cnt[((it + 1) % 3) * 16 + tid], 0ull,
                           __ATOMIC_RELAXED, __HIP_MEMORY_SCOPE_AGENT);
    }

    // ---- drain, then signal arrival (count + fixed-point err) ----
    asm volatile("s_waitcnt vmcnt(0)" ::: "memory");
    __syncthreads();
    if (tid == 0) {
      float be = swerr[it & 1][0] + swerr[it & 1][1] + swerr[it & 1][2] +
                 swerr[it & 1][3] + swerr[it & 1][4] + swerr[it & 1][5] +
                 swerr[it & 1][6] + swerr[it & 1][7];
      u64 inc = (1ull << 44) | (u64)(fminf(be, 250000.f) * 4096.0f);
      __hip_atomic_fetch_add(&cnt[(it % 3) * 16 + batch], inc,
                             __ATOMIC_RELAXED, __HIP_MEMORY_SCOPE_AGENT);
    }
  }

  // ---- final: wvr holds converged wv; accumulate transport cost ----
  float wcost = 0.f;
#pragma unroll
  for (int rr = 0; rr < 4; ++rr) {
    float s = 0.f;
#pragma unroll
    for (int t2 = 0; t2 < 16; ++t2)
      s = fmaf(kfr[rr][t2] * wvr[t2], -EPS * __logf(kfr[rr][t2]), s);  // pi*C, C=-eps log K
    s = wave_reduce_sum(s) * wu_reg[rr];
    if (lane == 0) wcost += s;
  }
  if (lane == 0) swerr[0][w] = wcost;   // safe: prior swerr reads all consumed
  __syncthreads();
  if (tid == 0) {
    float t = swerr[0][0] + swerr[0][1] + swerr[0][2] + swerr[0][3] +
              swerr[0][4] + swerr[0][5] + swerr[0][6] + swerr[0][7];
    atomicAdd(out + batch, t);
  }
}

extern "C" void kernel_launch(void* const* d_in, const int* in_sizes, int n_in,
                              void* d_out, int out_size, void* d_ws, size_t ws_size,
                              hipStream_t stream) {
  const float* x = (const float*)d_in[0];
  const float* y = (const float*)d_in[1];
  const float* nu = (const float*)d_in[2];
  float* out = (float*)d_out;
  float* ws = (float*)d_ws;

  ushort* xb = (ushort*)(ws + OFF_XB);
  ushort* yb = (ushort*)(ws + OFF_YB);
  float* nx = ws + OFF_NX;
  float* ny = ws + OFF_NY;
  float* nup = ws + OFF_NUP;
  float* cs = ws + OFF_CS;
  u64* cnt = (u64*)(ws + OFF_CNT);

  prep_kernel<<<2048, 256, 0, stream>>>(x, y, xb, yb, nx, ny, nu, nup, cs,
                                        (int*)cnt, out);

  void* args[] = {(void*)&xb, (void*)&yb, (void*)&nx,  (void*)&ny,
                  (void*)&cs, (void*)&nup, (void*)&cnt, (void*)&out};
  hipLaunchCooperativeKernel(reinterpret_cast<void*>(&fused_kernel),
                             dim3(GBLK), dim3(TBLK), args, 0, stream);
}

// Round 8
// 102.381 us; speedup vs baseline: 1.5098x; 1.5098x over previous
//
#include <hip/hip_runtime.h>
#include <math.h>

#define EPS      0.1f
#define INV_EPS  10.0f
#define THRESH   0.1f
#define MAX_IT   20

// Problem sizes (fixed by reference setup_inputs)
#define BB 4
#define NN 1024
#define MM 1024
#define DD 512

#define MU_P (1.0f / 1024.0f + 1e-8f)

// Sinkhorn loop config: 128 blocks x 512 threads, 32 rows/block, 4 rows/wave
// (PROVEN best: rounds 0/1). Launched as a REGULAR kernel: the grid barrier is
// our own flag scheme (no cooperative-groups API); co-residency is structural
// (128 blocks x 1 CU on an empty 256-CU device). Cooperative launch only added
// graph-capture overhead.
#define GBLK 128
#define TBLK 512

// workspace layout (float offsets)
#define OFF_K    ((size_t)0)                   // K = exp(-C/eps) [B,N,M] bf16 (8.4 MB)
#define OFF_XB   ((size_t)2097152)             // x in bf16 [B,N,D] (4.2 MB)
#define OFF_YB   ((size_t)3145728)             // y in bf16 [B,M,D] (4.2 MB)
#define OFF_NX   ((size_t)4194304)             // |x_i| [B*N]
#define OFF_NY   (OFF_NX + 4096)               // |y_j| [B*M]
#define OFF_NUP  (OFF_NY + 4096)               // nu + 1e-8 [B*M]
#define OFF_CS   (OFF_NUP + 4096)              // colsum rotation [3][4096]
#define OFF_FLG  (OFF_CS + 12288)              // barrier flags [2][128] ulong

#define GLDA 40  // padded ushort row stride (80 B): bank-balanced, 16B-aligned rows

typedef __bf16 bf16x8 __attribute__((ext_vector_type(8)));
typedef float f32x4 __attribute__((ext_vector_type(4)));
typedef unsigned long long u64;

__device__ __forceinline__ float wave_reduce_sum(float x) {
#pragma unroll
  for (int off = 32; off > 0; off >>= 1) x += __shfl_xor(x, off, 64);
  return x;
}

// pack two floats to bf16x2 (RNE via compiler cast)
__device__ __forceinline__ uint pk2(float a, float b) {
  __bf16 ha = (__bf16)a, hb = (__bf16)b;
  return (uint)*(ushort*)&ha | ((uint)*(ushort*)&hb << 16);
}

// -------- prep: fp32 norms of x/y rows (from ORIGINAL fp32), x/y -> bf16,
// sinkhorn state init (merged). One wave per 512-float row. --------
__global__ void __launch_bounds__(256) prep_kernel(const float* __restrict__ x,
                                                   const float* __restrict__ y,
                                                   ushort* __restrict__ xb,
                                                   ushort* __restrict__ yb,
                                                   float* __restrict__ nx,
                                                   float* __restrict__ ny,
                                                   const float* __restrict__ nu,
                                                   float* nup, float* colsum,
                                                   int* flagsi, float* out) {
  const int tid = threadIdx.x;
  int gt = blockIdx.x * 256 + tid;
  if (gt < BB * MM) {
    nup[gt] = nu[gt] + 1e-8f;
    colsum[4096 + gt] = 0.f;      // colsum[1] is iteration 0's add target
  }
  if (gt < 512) flagsi[gt] = 0;   // 2 x 128 ulong flag slots
  if (gt < BB) out[gt] = 0.f;

  const int w = tid >> 6, lane = tid & 63;
  const int r = blockIdx.x * 4 + w;                 // 0..8191
  const bool isx = (r < BB * NN);
  const float* src = isx ? (x + (size_t)r * DD)
                         : (y + (size_t)(r - BB * NN) * DD);
  ushort* dst = isx ? (xb + (size_t)r * DD)
                    : (yb + (size_t)(r - BB * NN) * DD);
  const float4* s4 = (const float4*)src;
  float4 a = s4[lane * 2];          // 8 contiguous floats per lane
  float4 b = s4[lane * 2 + 1];
  float ss = a.x * a.x + a.y * a.y + a.z * a.z + a.w * a.w +
             b.x * b.x + b.y * b.y + b.z * b.z + b.w * b.w;
  uint4 pk = make_uint4(pk2(a.x, a.y), pk2(a.z, a.w), pk2(b.x, b.y), pk2(b.z, b.w));
  *(uint4*)(dst + lane * 8) = pk;
  ss = wave_reduce_sum(ss);
  if (lane == 0) {
    float n = sqrtf(ss);
    if (isx) nx[r] = n; else ny[r - BB * NN] = n;
  }
}

// -------- MFMA bf16 GEMM (bf16-staged): dot = X Y^T, 128x64 tile, 256 thr,
// grid (16,8,4) = 512 blocks -> 2 independent blocks per CU.
// 4 waves of 4x2 16x16x32 frags; epilogue K = exp(-(1-dot/den)/eps), bf16. --------
__global__ void __launch_bounds__(256) gemm_kernel(const ushort* __restrict__ xb,
                                                   const ushort* __restrict__ yb,
                                                   const float* __restrict__ nxg,
                                                   const float* __restrict__ nyg,
                                                   ushort* __restrict__ K) {
  __shared__ ushort Ah[128 * GLDA];    // 10.2 KB
  __shared__ ushort Bh[64 * GLDA];     // 5.1 KB
  __shared__ float s_nx[128], s_ny[64];

  const int b = blockIdx.z;
  const int i0 = blockIdx.y * 128;   // m-tile (8)
  const int j0 = blockIdx.x * 64;    // n-tile (16)
  const int t = threadIdx.x;
  const int w = t >> 6, lane = t & 63;
  const int m16 = lane & 15, q = lane >> 4;
  const int wm = (w & 1) * 64, wn = (w >> 1) * 32;

  // staging: A 128 rows x 32 halves (2 thr/row, 16 halves each = 2 uint4),
  //          B  64 rows x 32 halves (4 thr/row,  8 halves each = 1 uint4)
  const int srA = t >> 1, soA = (t & 1) * 16;
  const int srB = t >> 2, soB = (t & 3) * 8;

  const ushort* xrow = xb + ((size_t)b * NN + i0 + srA) * DD + soA;
  const ushort* yrow = yb + ((size_t)b * MM + j0 + srB) * DD + soB;

  f32x4 acc[4][2];
#pragma unroll
  for (int mi = 0; mi < 4; ++mi)
#pragma unroll
    for (int ni = 0; ni < 2; ++ni) acc[mi][ni] = (f32x4)0.f;

  for (int k0 = 0; k0 < DD; k0 += 32) {
    uint4 av0 = *(const uint4*)(xrow + k0);
    uint4 av1 = *(const uint4*)(xrow + k0 + 8);
    uint4 bv0 = *(const uint4*)(yrow + k0);
    __syncthreads();
    *(uint4*)&Ah[srA * GLDA + soA] = av0;
    *(uint4*)&Ah[srA * GLDA + soA + 8] = av1;
    *(uint4*)&Bh[srB * GLDA + soB] = bv0;
    __syncthreads();

    bf16x8 ahf[4], bhf[2];
#pragma unroll
    for (int mi = 0; mi < 4; ++mi)
      ahf[mi] = *(const bf16x8*)&Ah[(wm + mi * 16 + m16) * GLDA + q * 8];
#pragma unroll
    for (int ni = 0; ni < 2; ++ni)
      bhf[ni] = *(const bf16x8*)&Bh[(wn + ni * 16 + m16) * GLDA + q * 8];
#pragma unroll
    for (int mi = 0; mi < 4; ++mi)
#pragma unroll
      for (int ni = 0; ni < 2; ++ni)
        acc[mi][ni] = __builtin_amdgcn_mfma_f32_16x16x32_bf16(ahf[mi], bhf[ni], acc[mi][ni], 0, 0, 0);
  }

  // epilogue: K = exp(-(1 - dot/den)/eps), bf16
  if (t < 128) s_nx[t] = nxg[b * NN + i0 + t];
  else if (t < 192) s_ny[t - 128] = nyg[b * MM + j0 + t - 128];
  __syncthreads();

#pragma unroll
  for (int mi = 0; mi < 4; ++mi)
#pragma unroll
    for (int ni = 0; ni < 2; ++ni)
#pragma unroll
      for (int r = 0; r < 4; ++r) {
        const int m = wm + mi * 16 + q * 4 + r;
        const int n = wn + ni * 16 + m16;
        float den = fmaxf(s_nx[m] * s_ny[n], 1e-8f);
        float cv = 1.0f - acc[mi][ni][r] / den;
        float kf = __expf(-cv * INV_EPS);
        __bf16 hb = (__bf16)kf;
        K[((size_t)b * NN + i0 + m) * MM + j0 + n] = *(ushort*)&hb;
      }
}

__device__ __forceinline__ void unpack8(uint4 k, float* kf) {
  kf[0] = __uint_as_float(k.x << 16);
  kf[1] = __uint_as_float(k.x & 0xffff0000u);
  kf[2] = __uint_as_float(k.y << 16);
  kf[3] = __uint_as_float(k.y & 0xffff0000u);
  kf[4] = __uint_as_float(k.z << 16);
  kf[5] = __uint_as_float(k.z & 0xffff0000u);
  kf[6] = __uint_as_float(k.w << 16);
  kf[7] = __uint_as_float(k.w & 0xffff0000u);
}

// -------- persistent Sinkhorn, ONE barrier per iteration (round-1 verbatim) --------
// K hoisted into registers once (4 rows/wave x 16 cols/lane = 64 VGPR fp32).
// rowsum_i = sum_j K_ij wv_j ; u_i = eps(log mu' - log rowsum_i); wu_i = mu'/rowsum_i
// colsum_j = sum_i K_ij wu_i (atomic-accumulated grid-wide, 3-buffer rotation)
// wv_j = nu'_j / colsum_j (recomputed LOCALLY by every block -> no v-barrier)
// barrier: all-to-all, one ulong {gen, err} per block, depth-2 ping-pong slots.
__global__ void __launch_bounds__(TBLK, 2) sinkhorn_kernel(
    const ushort* __restrict__ K, float* __restrict__ colsum,
    const float* __restrict__ nup, u64* __restrict__ flags,
    float* __restrict__ out) {
  const int tid = threadIdx.x;
  const int bid = blockIdx.x;
  const int lane = tid & 63;
  const int w = tid >> 6;                 // 0..7
  const int b = bid >> 5;                 // batch (32 blocks per batch)
  const int rbase = (bid & 31) * 32;      // first owned row within batch

  __shared__ float swv[1024];
  __shared__ float spart[8][1024];        // 32 KB per-wave column partials
  __shared__ float s_red;
  __shared__ int s_conv;

  const float eps_log_mu = EPS * __logf(MU_P);
  float u_prev[4] = {0.f, 0.f, 0.f, 0.f};
  float wu_reg[4] = {0.f, 0.f, 0.f, 0.f};
  int T = 0;

  // ---- hoist this wave's 4 K-rows into registers, unpacked fp32 ----
  float kf[4][16];
#pragma unroll
  for (int rr = 0; rr < 4; ++rr) {
    const uint4* kp = (const uint4*)(K + ((size_t)b * NN + rbase + w * 4 + rr) * MM);
    uint4 k0 = kp[lane];
    uint4 k1 = kp[lane + 64];
    unpack8(k0, kf[rr]);
    unpack8(k1, kf[rr] + 8);
  }

  for (int it = 0; it < MAX_IT; ++it) {
    const int genv = it + 1;
    // ---- stage wv (local v reconstruction; it=0: v=0 -> wv=1) ----
    if (tid == 0) s_red = 0.f;
    if (it == 0) {
      swv[tid] = 1.f;
      swv[tid + 512] = 1.f;
    } else {
      const float* cs = colsum + (it % 3) * 4096 + b * MM;
      float c0 = __hip_atomic_load(cs + tid, __ATOMIC_RELAXED, __HIP_MEMORY_SCOPE_AGENT);
      float c1 = __hip_atomic_load(cs + tid + 512, __ATOMIC_RELAXED, __HIP_MEMORY_SCOPE_AGENT);
      swv[tid] = nup[b * MM + tid] / c0;
      swv[tid + 512] = nup[b * MM + tid + 512] / c1;
    }
    __syncthreads();

    float wvr[16];
    {
      const float4* wp = (const float4*)swv;
      *(float4*)&wvr[0] = wp[lane * 2];
      *(float4*)&wvr[4] = wp[lane * 2 + 1];
      *(float4*)&wvr[8] = wp[128 + lane * 2];
      *(float4*)&wvr[12] = wp[129 + lane * 2];
    }
    float creg[16];
#pragma unroll
    for (int t2 = 0; t2 < 16; ++t2) creg[t2] = 0.f;

    float werr = 0.f;
#pragma unroll
    for (int rr = 0; rr < 4; ++rr) {
      float s = 0.f;
#pragma unroll
      for (int t2 = 0; t2 < 16; ++t2) s = fmaf(kf[rr][t2], wvr[t2], s);
      s = wave_reduce_sum(s);
      float unv = eps_log_mu - EPS * __logf(s);
      werr += fabsf(unv - u_prev[rr]);
      u_prev[rr] = unv;
      float wu = MU_P / s;          // exp(u_new/eps), exactly
      wu_reg[rr] = wu;
#pragma unroll
      for (int t2 = 0; t2 < 16; ++t2) creg[t2] = fmaf(wu, kf[rr][t2], creg[t2]);
    }
    if (lane == 0) atomicAdd(&s_red, werr);

    // publish per-wave column partials to LDS
    {
      float* pr = &spart[w][0];
      *(float4*)&pr[lane * 8] = *(float4*)&creg[0];
      *(float4*)&pr[lane * 8 + 4] = *(float4*)&creg[4];
      *(float4*)&pr[512 + lane * 8] = *(float4*)&creg[8];
      *(float4*)&pr[512 + lane * 8 + 4] = *(float4*)&creg[12];
    }
    __syncthreads();

    // cross-wave reduce + atomic add into next colsum; zero rotation buffer
    {
      float* csn = colsum + ((it + 1) % 3) * 4096 + b * MM;
      const int j0 = tid * 2;
      float s0 = 0.f, s1 = 0.f;
#pragma unroll
      for (int ww = 0; ww < 8; ++ww) {
        float2 p = *(const float2*)&spart[ww][j0];
        s0 += p.x;
        s1 += p.y;
      }
      unsafeAtomicAdd(&csn[j0], s0);
      unsafeAtomicAdd(&csn[j0 + 1], s1);
      if (tid < 32) {
        float* csz = colsum + ((it + 2) % 3) * 4096;
        __hip_atomic_store(&csz[bid * 32 + tid], 0.f, __ATOMIC_RELAXED, __HIP_MEMORY_SCOPE_AGENT);
      }
    }

    // ---- all-to-all barrier: publish {gen, err}, poll, local conv decision ----
    asm volatile("s_waitcnt vmcnt(0)" ::: "memory");
    __syncthreads();
    if (tid == 0) {
      u64 f = ((u64)(uint)genv << 32) | (u64)__float_as_uint(s_red);
      __hip_atomic_store(&flags[(genv & 1) * GBLK + bid], f, __ATOMIC_RELAXED, __HIP_MEMORY_SCOPE_AGENT);
    }
    if (tid < 64) {
      const u64* fl = flags + (genv & 1) * GBLK;
      u64 f0, f1;
      for (;;) {
        f0 = __hip_atomic_load(fl + tid, __ATOMIC_RELAXED, __HIP_MEMORY_SCOPE_AGENT);
        f1 = __hip_atomic_load(fl + tid + 64, __ATOMIC_RELAXED, __HIP_MEMORY_SCOPE_AGENT);
        if (__all(((f0 >> 32) >= (u64)genv) && ((f1 >> 32) >= (u64)genv))) break;
        __builtin_amdgcn_s_sleep(1);
      }
      float e = __uint_as_float((uint)f0) + __uint_as_float((uint)f1);
      e = wave_reduce_sum(e);
      if (tid == 0) s_conv = (e * (1.0f / (float)BB) < THRESH) ? 1 : 0;
    }
    __syncthreads();
    T = it;
    if (s_conv) break;
  }

  // ---- final: reconstruct converged wv locally, accumulate transport cost ----
  {
    const float* cs = colsum + ((T + 1) % 3) * 4096 + b * MM;
    float c0 = __hip_atomic_load(cs + tid, __ATOMIC_RELAXED, __HIP_MEMORY_SCOPE_AGENT);
    float c1 = __hip_atomic_load(cs + tid + 512, __ATOMIC_RELAXED, __HIP_MEMORY_SCOPE_AGENT);
    swv[tid] = nup[b * MM + tid] / c0;
    swv[tid + 512] = nup[b * MM + tid + 512] / c1;
  }
  if (tid == 0) s_red = 0.f;
  __syncthreads();

  float wvr[16];
  {
    const float4* wp = (const float4*)swv;
    *(float4*)&wvr[0] = wp[lane * 2];
    *(float4*)&wvr[4] = wp[lane * 2 + 1];
    *(float4*)&wvr[8] = wp[128 + lane * 2];
    *(float4*)&wvr[12] = wp[129 + lane * 2];
  }

  float wcost = 0.f;
#pragma unroll
  for (int rr = 0; rr < 4; ++rr) {
    float s = 0.f;
#pragma unroll
    for (int t2 = 0; t2 < 16; ++t2)
      s = fmaf(kf[rr][t2] * wvr[t2], -EPS * __logf(kf[rr][t2]), s);   // pi * C, C = -eps log K
    s = wave_reduce_sum(s) * wu_reg[rr];
    if (lane == 0) wcost += s;
  }
  if (lane == 0) atomicAdd(&s_red, wcost);
  __syncthreads();
  if (tid == 0) atomicAdd(out + b, s_red);
}

extern "C" void kernel_launch(void* const* d_in, const int* in_sizes, int n_in,
                              void* d_out, int out_size, void* d_ws, size_t ws_size,
                              hipStream_t stream) {
  const float* x = (const float*)d_in[0];
  const float* y = (const float*)d_in[1];
  const float* nu = (const float*)d_in[2];
  float* out = (float*)d_out;
  float* ws = (float*)d_ws;

  ushort* K = (ushort*)(ws + OFF_K);
  ushort* xb = (ushort*)(ws + OFF_XB);
  ushort* yb = (ushort*)(ws + OFF_YB);
  float* nx = ws + OFF_NX;
  float* ny = ws + OFF_NY;
  float* nup = ws + OFF_NUP;
  float* cs = ws + OFF_CS;
  u64* flg = (u64*)(ws + OFF_FLG);

  prep_kernel<<<2048, 256, 0, stream>>>(x, y, xb, yb, nx, ny, nu, nup, cs, (int*)flg, out);
  gemm_kernel<<<dim3(16, 8, 4), 256, 0, stream>>>(xb, yb, nx, ny, K);

  // REGULAR launch (single-variable change vs round 1): the grid barrier is our
  // own flag scheme; 128 blocks on 256 empty CUs are structurally co-resident.
  sinkhorn_kernel<<<GBLK, TBLK, 0, stream>>>(K, cs, nup, flg, out);
}